// Round 3
// baseline (29.121 us; speedup 1.0000x reference)
//
#include <hip/hip_runtime.h>

// MultiHeadAttention_spatial_self: bs=32, T=2048, F=45 (15 nodes x 3 dims),
// 3 heads, d_k=1, fixed 15-joint skeleton graph.
// Round 3: 6 threads per position = (head, half) -> 384-thread blocks (6 waves),
// 64 positions per block -> 24 waves/CU = 6/SIMD (needs VGPR <= 85).
// Attention duplicated across s; 45x45 output projection split by output rows.

#define SLAB 2880  // 64 positions * 45 floats

__device__ __forceinline__ void glds16(const float* g, float* l) {
  __builtin_amdgcn_global_load_lds(
      (const __attribute__((address_space(1))) void*)g,
      (__attribute__((address_space(3))) void*)l, 16, 0, 0);
}

__device__ __forceinline__ float tmax15(const float* a) {
  // pairwise tree max over 15 elements, depth 4
  float m01 = fmaxf(a[0], a[1]), m23 = fmaxf(a[2], a[3]);
  float m45 = fmaxf(a[4], a[5]), m67 = fmaxf(a[6], a[7]);
  float m89 = fmaxf(a[8], a[9]), mab = fmaxf(a[10], a[11]);
  float mcd = fmaxf(a[12], a[13]);
  float x0 = fmaxf(m01, m23), x1 = fmaxf(m45, m67);
  float x2 = fmaxf(m89, mab), x3 = fmaxf(mcd, a[14]);
  return fmaxf(fmaxf(x0, x1), fmaxf(x2, x3));
}

__global__ void __launch_bounds__(384, 6)
mha_spatial_kernel(const float* __restrict__ q, const float* __restrict__ k,
                   const float* __restrict__ v,
                   const float* __restrict__ wq, const float* __restrict__ bq,
                   const float* __restrict__ wk, const float* __restrict__ bk,
                   const float* __restrict__ wv, const float* __restrict__ bv,
                   const float* __restrict__ wo, const float* __restrict__ bo,
                   float* __restrict__ out)
{
  // Unmasked (n,m) pairs of the 15x15 grid: diag + (child,parent) + (parent,child).
  constexpr int PN[43] = {0,1,2,3,4,5,6,7,8,9,10,11,12,13,14,
                          1,0, 2,1, 3,2, 4,0, 5,4, 6,5, 7,0,
                          8,7, 9,8, 10,9, 11,8, 12,11, 13,8, 14,13};
  constexpr int PM[43] = {0,1,2,3,4,5,6,7,8,9,10,11,12,13,14,
                          0,1, 1,2, 2,3, 0,4, 4,5, 5,6, 0,7,
                          7,8, 8,9, 9,10, 8,11, 11,12, 8,13, 13,14};

  __shared__ float sm[3 * SLAB];
  const int tid = threadIdx.x;
  const int p = tid & 63;                 // position within block
  const int w = tid >> 6;                 // wave 0..5
  const int h = (w >= 3) ? (w - 3) : w;   // head (wave-uniform)
  const int s = (w >= 3) ? 1 : 0;         // output-row half (wave-uniform)
  const int hu = __builtin_amdgcn_readfirstlane(h);
  const int su = __builtin_amdgcn_readfirstlane(s);
  const size_t base = (size_t)blockIdx.x * SLAB;

  // ---- stage q, k, v slabs (64 pos x 45 floats each) into LDS, coalesced ----
  {
    const float* gq = q + base;
    const float* gk = k + base;
    const float* gv = v + base;
    float* l0 = sm;
    float* l1 = sm + SLAB;
    float* l2 = sm + 2 * SLAB;
#pragma unroll
    for (int i = 0; i < 2; ++i) {
      const int idx = i * 384 + tid;      // float4 granule index, 720 per slab
      if (idx < 720) {
        const int off = idx * 4;          // lane-linear -> matches glds lane x 16B
        glds16(gq + off, l0 + off);
        glds16(gk + off, l1 + off);
        glds16(gv + off, l2 + off);
      }
    }
  }

  // this head's projection weights (wave-uniform -> SGPRs)
  const float wq0 = wq[hu*3+0], wq1 = wq[hu*3+1], wq2 = wq[hu*3+2], bq0 = bq[hu];
  const float wk0 = wk[hu*3+0], wk1 = wk[hu*3+1], wk2 = wk[hu*3+2], bk0 = bk[hu];
  const float wv0 = wv[hu*3+0], wv1 = wv[hu*3+1], wv2 = wv[hu*3+2], bv0 = bv[hu];

  __syncthreads();  // drains global_load_lds + barrier

  const float* xq = sm + p * 45;          // own row: x[n][d] = row[d*15+n]
  const float* xk = sm + SLAB + p * 45;
  const float* xv = sm + 2 * SLAB + p * 45;

  // ---- per-head projection + masked attention (duplicated in both s-threads) ----
  float aq[15], ak[15], vv[15];
#pragma unroll
  for (int n = 0; n < 15; ++n) {
    aq[n] = fabsf(bq0 + xq[n] * wq0 + xq[15 + n] * wq1 + xq[30 + n] * wq2);
    ak[n] = fabsf(bk0 + xk[n] * wk0 + xk[15 + n] * wk1 + xk[30 + n] * wk2);
    vv[n] = bv0 + xv[n] * wv0 + xv[15 + n] * wv1 + xv[30 + n] * wv2;
  }
  // softmax shift: any uniform constant works. Use ub = max(aq)*max(ak) >= all
  // scores; gap <= ub <~ 50 for this data, exp(-50) >> f32 min normal. Avoids
  // the 43-deep serial fmax chain over pair products.
  const float mx = tmax15(aq) * tmax15(ak);
  float Z0 = 0.0f, Z1 = 0.0f;
  float oh[15];
#pragma unroll
  for (int n = 0; n < 15; ++n) oh[n] = 0.0f;
#pragma unroll
  for (int i = 0; i < 43; ++i) {
    const float e = __expf(aq[PN[i]] * ak[PM[i]] - mx);
    if (i & 1) Z1 += e; else Z0 += e;
    oh[PN[i]] += e * vv[PM[i]];
  }
  const float rz = 1.0f / (Z0 + Z1);

  __syncthreads();  // all q/k/v slab reads done -> slab 0 reusable

  // ---- exchange concat across heads via LDS (slab 0): concat[p][n*3+h] ----
  {
    float* crow = sm + p * 45;
#pragma unroll
    for (int n = 0; n < 15; ++n) {
      const bool mine = su ? (n >= 8) : (n < 8);  // split writes across s
      if (mine) crow[n * 3 + hu] = oh[n] * rz;    // stride 45: conflict-free
    }
  }
  __syncthreads();

  // ---- output projection: thread (h,s) computes f = h*15+s*8 .. (+7 or +6) ----
  {
    const int fbase = hu * 15 + su * 8;
    const int nj = su ? 7 : 8;
    float cg[45];
    const float* crow = sm + p * 45;
#pragma unroll
    for (int g = 0; g < 45; ++g) cg[g] = crow[g];
    float acc[8];
#pragma unroll
    for (int j = 0; j < 8; ++j) {
      const int f = (fbase + j < 45) ? (fbase + j) : 44;  // clamp dead lane-row
      acc[j] = bo[f];
    }
#pragma unroll
    for (int g = 0; g < 45; ++g) {
#pragma unroll
      for (int j = 0; j < 8; ++j) {
        const int f = (fbase + j < 45) ? (fbase + j) : 44;
        acc[j] = fmaf(cg[g], wo[f * 45 + g], acc[j]);  // wo idx scalar -> s_load
      }
    }
    // stage y into slab 1 (k-slab no longer needed)
    float* yrow = sm + SLAB + p * 45;
#pragma unroll
    for (int j = 0; j < 8; ++j)
      if (j < nj) yrow[fbase + j] = acc[j];
  }
  __syncthreads();

  // ---- coalesced store of the block's 2880 outputs ----
  float* gout = out + base;
  const float* ysrc = sm + SLAB;
#pragma unroll
  for (int i = 0; i < 2; ++i) {
    const int idx = i * 384 + tid;
    if (idx < 720)
      *(float4*)(gout + idx * 4) = *(const float4*)(ysrc + idx * 4);
  }
}

extern "C" void kernel_launch(void* const* d_in, const int* in_sizes, int n_in,
                              void* d_out, int out_size, void* d_ws, size_t ws_size,
                              hipStream_t stream) {
  const float* q  = (const float*)d_in[0];
  const float* k  = (const float*)d_in[1];
  const float* v  = (const float*)d_in[2];
  const float* wq = (const float*)d_in[3];
  const float* bq = (const float*)d_in[4];
  const float* wk = (const float*)d_in[5];
  const float* bk = (const float*)d_in[6];
  const float* wv = (const float*)d_in[7];
  const float* bv = (const float*)d_in[8];
  const float* wo = (const float*)d_in[9];
  const float* bo = (const float*)d_in[10];
  float* out = (float*)d_out;

  // 65536 positions, 64 per block, 6 threads (head x half) per position
  hipLaunchKernelGGL(mha_spatial_kernel, dim3(1024), dim3(384), 0, stream,
                     q, k, v, wq, bq, wk, bk, wv, bv, wo, bo, out);
}

// Round 4
// 25.354 us; speedup vs baseline: 1.1486x; 1.1486x over previous
//
#include <hip/hip_runtime.h>

// MultiHeadAttention_spatial_self: bs=32, T=2048, F=45 (15 nodes x 3 dims),
// 3 heads, d_k=1, fixed 15-joint skeleton graph.
// Round 4: 5 threads per position -> 320-thread blocks (5 waves), 64 positions
// per block, grid 1024 = 4 blocks/CU = 20 waves/CU = 5 waves/SIMD.
// Needs VGPR <= 102 (512/5): out-proj split 9 rows/wave, cg via 12x ds_read_b128.

#define SLAB 2880   // 64 positions * 45 floats
#define CPAD 52     // padded concat row: 208 B, 16B-aligned, good bank spread
#define YOFF 3328   // y region starts after concat region (64*52)

__device__ __forceinline__ void glds16(const float* g, float* l) {
  __builtin_amdgcn_global_load_lds(
      (const __attribute__((address_space(1))) void*)g,
      (__attribute__((address_space(3))) void*)l, 16, 0, 0);
}

__device__ __forceinline__ float tmax15(const float* a) {
  // pairwise tree max over 15 elements, depth 4
  float m01 = fmaxf(a[0], a[1]), m23 = fmaxf(a[2], a[3]);
  float m45 = fmaxf(a[4], a[5]), m67 = fmaxf(a[6], a[7]);
  float m89 = fmaxf(a[8], a[9]), mab = fmaxf(a[10], a[11]);
  float mcd = fmaxf(a[12], a[13]);
  float x0 = fmaxf(m01, m23), x1 = fmaxf(m45, m67);
  float x2 = fmaxf(m89, mab), x3 = fmaxf(mcd, a[14]);
  return fmaxf(fmaxf(x0, x1), fmaxf(x2, x3));
}

__global__ void __launch_bounds__(320, 5)
mha_spatial_kernel(const float* __restrict__ q, const float* __restrict__ k,
                   const float* __restrict__ v,
                   const float* __restrict__ wq, const float* __restrict__ bq,
                   const float* __restrict__ wk, const float* __restrict__ bk,
                   const float* __restrict__ wv, const float* __restrict__ bv,
                   const float* __restrict__ wo, const float* __restrict__ bo,
                   float* __restrict__ out)
{
  // Unmasked (n,m) pairs of the 15x15 grid: diag + (child,parent) + (parent,child).
  constexpr int PN[43] = {0,1,2,3,4,5,6,7,8,9,10,11,12,13,14,
                          1,0, 2,1, 3,2, 4,0, 5,4, 6,5, 7,0,
                          8,7, 9,8, 10,9, 11,8, 12,11, 13,8, 14,13};
  constexpr int PM[43] = {0,1,2,3,4,5,6,7,8,9,10,11,12,13,14,
                          0,1, 1,2, 2,3, 0,4, 4,5, 5,6, 0,7,
                          7,8, 8,9, 9,10, 8,11, 11,12, 8,13, 13,14};

  __shared__ float sm[3 * SLAB];  // 8640 floats = 34.56 KB
  const int tid = threadIdx.x;
  const int p = tid & 63;                                  // position in block
  const int wu = __builtin_amdgcn_readfirstlane(tid >> 6); // wave 0..4 (SGPR)
  const int h = (wu >= 3) ? (wu - 3) : wu;                 // attention head

  const size_t base = (size_t)blockIdx.x * SLAB;

  // ---- stage q, k, v slabs (64 pos x 45 floats each) into LDS, coalesced ----
  {
    const float* gq = q + base;
    const float* gk = k + base;
    const float* gv = v + base;
    float* l0 = sm;
    float* l1 = sm + SLAB;
    float* l2 = sm + 2 * SLAB;
#pragma unroll
    for (int i = 0; i < 3; ++i) {
      const int idx = i * 320 + tid;      // float4 granule index, 720 per slab
      if (idx < 720) {
        const int off = idx * 4;          // lane-linear -> matches glds lane x 16B
        glds16(gq + off, l0 + off);
        glds16(gk + off, l1 + off);
        glds16(gv + off, l2 + off);
      }
    }
  }

  // this head's projection weights (wave-uniform -> SGPRs)
  const float wq0 = wq[h*3+0], wq1 = wq[h*3+1], wq2 = wq[h*3+2], bq0 = bq[h];
  const float wk0 = wk[h*3+0], wk1 = wk[h*3+1], wk2 = wk[h*3+2], bk0 = bk[h];
  const float wv0 = wv[h*3+0], wv1 = wv[h*3+1], wv2 = wv[h*3+2], bv0 = bv[h];

  __syncthreads();  // drains global_load_lds + barrier

  // ---- per-head projection + masked attention (heads 0,1 duplicated x2) ----
  float oh[15];
  float rz;
  {
    const float* xq = sm + p * 45;        // own row: x[n][d] = row[d*15+n]
    const float* xk = sm + SLAB + p * 45;
    const float* xv = sm + 2 * SLAB + p * 45;
    float aq[15], ak[15], vv[15];
#pragma unroll
    for (int n = 0; n < 15; ++n) {
      aq[n] = fabsf(bq0 + xq[n] * wq0 + xq[15 + n] * wq1 + xq[30 + n] * wq2);
      ak[n] = fabsf(bk0 + xk[n] * wk0 + xk[15 + n] * wk1 + xk[30 + n] * wk2);
      vv[n] = bv0 + xv[n] * wv0 + xv[15 + n] * wv1 + xv[30 + n] * wv2;
    }
    // softmax shift: any uniform constant works; ub = max(aq)*max(ak) >= all
    // scores (gap <~ 50, exp(-50) >> f32 min normal). Depth-4 trees, no
    // 43-deep serial fmax chain.
    const float mx = tmax15(aq) * tmax15(ak);
    float Z0 = 0.0f, Z1 = 0.0f;
#pragma unroll
    for (int n = 0; n < 15; ++n) oh[n] = 0.0f;
#pragma unroll
    for (int i = 0; i < 43; ++i) {
      const float e = __expf(aq[PN[i]] * ak[PM[i]] - mx);
      if (i & 1) Z1 += e; else Z0 += e;
      oh[PN[i]] += e * vv[PM[i]];
    }
    rz = 1.0f / (Z0 + Z1);
  }

  __syncthreads();  // all q/k/v slab reads done -> LDS reusable

  // ---- exchange concat via LDS, padded rows: concat[p][n*3+h] at p*CPAD ----
  {
    float* crow = sm + p * CPAD;
#pragma unroll
    for (int n = 0; n < 15; ++n) {
      // head 2 owned by wave 2 alone; heads 0/1 split between waves (0,3)/(1,4)
      const bool mine = (wu == 2) || ((wu < 3) ? (n < 8) : (n >= 8));
      if (mine) crow[n * 3 + h] = oh[n] * rz;
    }
  }
  __syncthreads();

  // ---- output projection: wave w computes rows f = w*9 .. w*9+8 ----
  {
    float cg[48];
    const float4* c4 = (const float4*)(sm + p * CPAD);  // 16B-aligned
#pragma unroll
    for (int c = 0; c < 12; ++c) {
      const float4 t = c4[c];
      cg[c*4+0] = t.x; cg[c*4+1] = t.y; cg[c*4+2] = t.z; cg[c*4+3] = t.w;
    }
    const int fbase = wu * 9;
    float acc[9];
#pragma unroll
    for (int j = 0; j < 9; ++j) acc[j] = bo[fbase + j];
#pragma unroll
    for (int g = 0; g < 45; ++g) {
#pragma unroll
      for (int j = 0; j < 9; ++j)
        acc[j] = fmaf(cg[g], wo[(fbase + j) * 45 + g], acc[j]);  // wo -> s_load
    }
    float* yrow = sm + YOFF + p * 45;
#pragma unroll
    for (int j = 0; j < 9; ++j) yrow[fbase + j] = acc[j];  // stride 45: free
  }
  __syncthreads();

  // ---- coalesced store of the block's 2880 outputs ----
  float* gout = out + base;
  const float* ysrc = sm + YOFF;
#pragma unroll
  for (int i = 0; i < 3; ++i) {
    const int idx = i * 320 + tid;
    if (idx < 720)
      *(float4*)(gout + idx * 4) = *(const float4*)(ysrc + idx * 4);
  }
}

extern "C" void kernel_launch(void* const* d_in, const int* in_sizes, int n_in,
                              void* d_out, int out_size, void* d_ws, size_t ws_size,
                              hipStream_t stream) {
  const float* q  = (const float*)d_in[0];
  const float* k  = (const float*)d_in[1];
  const float* v  = (const float*)d_in[2];
  const float* wq = (const float*)d_in[3];
  const float* bq = (const float*)d_in[4];
  const float* wk = (const float*)d_in[5];
  const float* bk = (const float*)d_in[6];
  const float* wv = (const float*)d_in[7];
  const float* bv = (const float*)d_in[8];
  const float* wo = (const float*)d_in[9];
  const float* bo = (const float*)d_in[10];
  float* out = (float*)d_out;

  // 65536 positions, 64 per block, 5 threads (waves) per position
  hipLaunchKernelGGL(mha_spatial_kernel, dim3(1024), dim3(320), 0, stream,
                     q, k, v, wq, bq, wk, bk, wv, bv, wo, bo, out);
}